// Round 6
// baseline (487.822 us; speedup 1.0000x reference)
//
#include <hip/hip_runtime.h>
#include <hip/hip_bf16.h>
#include <stdint.h>

typedef __bf16 bf16x8 __attribute__((ext_vector_type(8)));
typedef ushort u16x8 __attribute__((ext_vector_type(8)));
typedef uint u32x4 __attribute__((ext_vector_type(4)));
typedef float f32x4 __attribute__((ext_vector_type(4)));
typedef float f32x16 __attribute__((ext_vector_type(16)));

#define NB_H 16
#define NB_KV 4
#define NB_HD 128
#define NB_B 2
#define NB_S 2048
#define NB_D 2048
#define NB_M (NB_B*NB_S)   /* 4096 */
#define NB_NQKV 3072
#define CAPF 50.0f
#define SCALEF 0.08838834764831845f

__device__ __forceinline__ ushort f2bf(float x){
  uint32_t u = __float_as_uint(x);
  u += 0x7fffu + ((u >> 16) & 1u);
  return (ushort)(u >> 16);
}
__device__ __forceinline__ float bf2f(ushort u){
  return __uint_as_float(((uint32_t)u) << 16);
}
__device__ __forceinline__ uint bfpack(float lo, float hi2){
  uint a = (uint)__builtin_bit_cast(unsigned short, (__bf16)lo);
  uint b = (uint)__builtin_bit_cast(unsigned short, (__bf16)hi2);
  return a | (b << 16);
}
__device__ __forceinline__ void gload_lds16(const void* g, void* l){
  __builtin_amdgcn_global_load_lds(
      (const __attribute__((address_space(1))) uint32_t*)g,
      (__attribute__((address_space(3))) uint32_t*)l, 16, 0, 0);
}

// ---------------- fused fp32 -> bf16 conversion (all 5 tensors, 1 launch) ----------------
__global__ __launch_bounds__(256) void cvt_all(const float* __restrict__ hs,
                                               const float* __restrict__ wq,
                                               const float* __restrict__ wk,
                                               const float* __restrict__ wv,
                                               const float* __restrict__ wo,
                                               ushort* __restrict__ hsb,
                                               ushort* __restrict__ wqkv,
                                               ushort* __restrict__ wob){
  int q = blockIdx.x * blockDim.x + threadIdx.x;   // grid sized exactly
  const float* src; ushort* dst; int i;
  if (q < 2097152)      { src = hs; dst = hsb;            i = q; }
  else if (q < 3145728) { src = wq; dst = wqkv;           i = q - 2097152; }
  else if (q < 3407872) { src = wk; dst = wqkv + 4194304; i = q - 3145728; }
  else if (q < 3670016) { src = wv; dst = wqkv + 5242880; i = q - 3407872; }
  else                  { src = wo; dst = wob;            i = q - 3670016; }
  float4 v = ((const float4*)src)[i];
  ushort4 o;
  o.x = f2bf(v.x); o.y = f2bf(v.y); o.z = f2bf(v.z); o.w = f2bf(v.w);
  ((ushort4*)dst)[i] = o;
}

// ---------------- bf16 GEMM: C[M][N] = A[M][K] * B[N][K]^T (1D grid + XCD swizzle) ----------------
__global__ __launch_bounds__(256) void gemm_bt(const ushort* __restrict__ A,
                                               const ushort* __restrict__ Bw,
                                               ushort* __restrict__ Cb,
                                               float* __restrict__ Cf,
                                               int M, int N, int K, int nbx){
  int nwg = gridDim.x;
  int cpx = nwg >> 3;
  int wg = blockIdx.x;
  int swz = (wg & 7) * cpx + (wg >> 3);
  int bx = swz % nbx, by = swz / nbx;

  __shared__ ushort As[128 * 32];
  __shared__ ushort Bs[128 * 32];
  int tid = threadIdx.x;
  int w = tid >> 6, l = tid & 63;
  int lr = l & 15, lk = l >> 4;
  int row0 = by * 128, col0 = bx * 128;
  int wm = w >> 1, wn = w & 1;

  f32x4 acc[4][4];
#pragma unroll
  for (int mi = 0; mi < 4; ++mi)
#pragma unroll
    for (int nj = 0; nj < 4; ++nj)
      acc[mi][nj] = f32x4{0.f, 0.f, 0.f, 0.f};

  for (int k0 = 0; k0 < K; k0 += 32) {
#pragma unroll
    for (int c = 0; c < 2; ++c) {
      int off = w * 2048 + c * 1024 + l * 16;
      int r = off >> 6;
      int cb = off & 63;
      gload_lds16(A + (size_t)(row0 + r) * K + k0 + (cb >> 1), (char*)As + off);
      gload_lds16(Bw + (size_t)(col0 + r) * K + k0 + (cb >> 1), (char*)Bs + off);
    }
    __syncthreads();
    bf16x8 af[4], bfr[4];
#pragma unroll
    for (int mi = 0; mi < 4; ++mi)
      af[mi] = *(const bf16x8*)(As + (wm * 64 + mi * 16 + lr) * 32 + lk * 8);
#pragma unroll
    for (int nj = 0; nj < 4; ++nj)
      bfr[nj] = *(const bf16x8*)(Bs + (wn * 64 + nj * 16 + lr) * 32 + lk * 8);
#pragma unroll
    for (int mi = 0; mi < 4; ++mi)
#pragma unroll
      for (int nj = 0; nj < 4; ++nj)
        acc[mi][nj] = __builtin_amdgcn_mfma_f32_16x16x32_bf16(af[mi], bfr[nj], acc[mi][nj], 0, 0, 0);
    __syncthreads();
  }

#pragma unroll
  for (int mi = 0; mi < 4; ++mi)
#pragma unroll
    for (int nj = 0; nj < 4; ++nj)
#pragma unroll
      for (int i = 0; i < 4; ++i) {
        int r = row0 + wm * 64 + mi * 16 + lk * 4 + i;
        int c = col0 + wn * 64 + nj * 16 + lr;
        float v = acc[mi][nj][i];
        if (Cb) Cb[(size_t)r * N + c] = f2bf(v);
        else    Cf[(size_t)r * N + c] = v;
      }
}

// ---------------- RoPE in-place on Q heads only (K's RoPE is fused into kv_repack) ----------------
__global__ __launch_bounds__(256) void rope_q(ushort* __restrict__ qkv,
                                              const float* __restrict__ cosb,
                                              const float* __restrict__ sinb){
  int idx = blockIdx.x * blockDim.x + threadIdx.x;   // NB_M*16*64 exactly
  int row = idx >> 10;
  int rem = idx & 1023;
  int head = rem >> 6;        // 0..15
  int d = rem & 63;
  size_t base = (size_t)row * NB_NQKV + head * 128 + d;
  float a = bf2f(qkv[base]);
  float b = bf2f(qkv[base + 64]);
  float c = cosb[row * 128 + d];
  float s = sinb[row * 128 + d];
  qkv[base]      = f2bf(a * c - b * s);
  qkv[base + 64] = f2bf(b * c + a * s);
}

// ---------------- K/V repack into MFMA-fragment layout (+ RoPE on K) ----------------
// grid: B*KV*(S/64) = 256 blocks x 256 thr. Per (b,kvh,kt64):
//   Kf[(t,dc)][lane] = roped K[s0+32t+ql][16dc+8hi+j]   (16 frags x 64 lanes x 8 bf16)
//   Vf[(c,dt)][lane] = V[s0+(2c+hi)*8+j][32dt+ql]
__global__ __launch_bounds__(256) void kv_repack(const ushort* __restrict__ qkv,
                                                 const float* __restrict__ cosb,
                                                 const float* __restrict__ sinb,
                                                 ushort* __restrict__ Kf,
                                                 ushort* __restrict__ Vf){
  __shared__ ushort Ks[64 * 136];
  __shared__ ushort Vs[64 * 136];
  const int blk = blockIdx.x;
  const int kt = blk & 31, kvh = (blk >> 5) & 3, b = blk >> 7;
  const int s0 = kt * 64;
  const int tid = threadIdx.x;
  {
    const int r = tid >> 2, c0 = tid & 3;
    const ushort* src = qkv + (size_t)(b * NB_S + s0 + r) * NB_NQKV + kvh * 128;
#pragma unroll
    for (int k = 0; k < 4; ++k) {
      int c = c0 + k * 4;
      *(u16x8*)(Ks + r * 136 + c * 8) = *(const u16x8*)(src + 2048 + c * 8);
      *(u16x8*)(Vs + r * 136 + c * 8) = *(const u16x8*)(src + 2560 + c * 8);
    }
  }
  __syncthreads();
  const int w = tid >> 6, l = tid & 63, ql = l & 31, hi = l >> 5;
  const size_t fbase = (size_t)((b * NB_KV + kvh) * 32 + kt) * 8192;
  // K fragments (with RoPE) — all state in ext-vectors (no address-taken locals)
#pragma unroll
  for (int i = 0; i < 4; ++i) {
    const int idx = i * 4 + w;          // = t*8 + dc
    const int t = idx >> 3, dc = idx & 7;
    const int row = t * 32 + ql;
    const int d0 = dc * 16 + hi * 8;
    u16x8 a  = *(const u16x8*)(Ks + row * 136 + d0);
    u16x8 p2 = *(const u16x8*)(Ks + row * 136 + (d0 ^ 64));
    const float* cr = cosb + (size_t)(b * NB_S + s0 + row) * 128 + d0;
    const float* sr = sinb + (size_t)(b * NB_S + s0 + row) * 128 + d0;
    const float sgn = (dc < 4) ? -1.f : 1.f;
    u16x8 outv;
#pragma unroll
    for (int j2 = 0; j2 < 8; ++j2) {
      float kv = bf2f(a[j2]), pv = bf2f(p2[j2]);
      outv[j2] = f2bf(fmaf(sgn * pv, sr[j2], kv * cr[j2]));
    }
    *(u16x8*)(Kf + fbase + ((size_t)idx * 64 + l) * 8) = outv;
  }
  // V fragments
#pragma unroll
  for (int i = 0; i < 4; ++i) {
    const int idx = i * 4 + w;          // = c*4 + dt
    const int c = idx >> 2, dt = idx & 3;
    const int col = dt * 32 + ql;
    u16x8 outv;
#pragma unroll
    for (int j2 = 0; j2 < 8; ++j2)
      outv[j2] = Vs[((2 * c + hi) * 8 + j2) * 136 + col];
    *(u16x8*)(Vf + fbase + ((size_t)idx * 64 + l) * 8) = outv;
  }
}

// ---------------- flash attention v6: fragment-layout K/V from L2, barrier-free, no spill ----------------
// grid: 2048 blocks x 128 thr (2 waves). Block = one 32-row q-tile; waves split k-tiles
// (interleaved) and merge exactly at the end (no-max softmax).
// decode: g = blk&7 -> (b,kvh) [XCD affinity]; inner = blk>>3: h_lo = inner&3,
//         qtile = 63 - (inner>>2) [heaviest first].
__global__ __launch_bounds__(128, 4) void attn_kernel(const ushort* __restrict__ qkv,
                                                      const ushort* __restrict__ Kf,
                                                      const ushort* __restrict__ Vf,
                                                      ushort* __restrict__ obuf){
  __shared__ float accbuf[2048];      // 2-phase split-k merge (8KB)
  __shared__ float lbuf[64];
  __shared__ ushort trbuf[32 * 140];  // epilogue transpose
  const int tid = threadIdx.x;
  const int w = tid >> 6, l = tid & 63;
  const int ql = l & 31, hi = l >> 5;
  const int blk = blockIdx.x;
  const int g = blk & 7;
  const int inner = blk >> 3;
  const int h_lo = inner & 3;
  const int qtile = 63 - (inner >> 2);
  const int b = g >> 2, kvh = g & 3;
  const int h = kvh * 4 + h_lo;
  const int q0 = qtile * 32;
  const int q = q0 + ql;
  const int nkt = (q0 + 95) >> 6;     // tiles with s0 <= q0+31

  const ushort* Kfb = Kf + (size_t)(b * NB_KV + kvh) * 262144 + l * 8;
  const ushort* Vfb = Vf + (size_t)(b * NB_KV + kvh) * 262144 + l * 8;

  // Q fragments: plain vector loads (Q pre-roped by rope_q)
  bf16x8 qf[8];
  {
    const ushort* qrow = qkv + (size_t)(b * NB_S + q) * NB_NQKV + h * 128 + hi * 8;
#pragma unroll
    for (int dc = 0; dc < 8; ++dc)
      qf[dc] = *(const bf16x8*)(qrow + dc * 16);
  }

  f32x16 acc[4];   // O^T accumulator: acc[dt] = 32d x 32q tile, col q = ql
#pragma unroll
  for (int dt = 0; dt < 4; ++dt)
#pragma unroll
    for (int r = 0; r < 16; ++r) acc[dt][r] = 0.f;
  float l_run = 0.f;

  const float K1 = SCALEF / CAPF;                  // s -> x
  const float KW = SCALEF * 1.4426950408889634f;   // s -> w (= cap*log2e*x)

  for (int kt = w; kt < nkt; kt += 2) {
    const int s0 = kt * 64;
    const ushort* kp = Kfb + (size_t)kt * 8192;
    const ushort* vp = Vfb + (size_t)kt * 8192;
    // S^T = mfma(K, Q): coalesced 16B/lane fragment loads (L2-resident)
    f32x16 st[2];
#pragma unroll
    for (int t = 0; t < 2; ++t) {
#pragma unroll
      for (int r = 0; r < 16; ++r) st[t][r] = 0.f;
#pragma unroll
      for (int dc = 0; dc < 8; ++dc) {
        bf16x8 kf = *(const bf16x8*)(kp + (t * 8 + dc) * 512);
        st[t] = __builtin_amdgcn_mfma_f32_32x32x16_bf16(kf, qf[dc], st[t], 0, 0, 0);
      }
    }
    // fused poly-tanh soft-cap + exp2 softmax (no max subtraction: capped <= 50)
    const bool full = (s0 + 63 <= q0);             // wave-uniform
    const int qmb = q - s0 - 4 * hi;               // mask: koff <= qmb
    float p[2][16];
    float rs = 0.f;
#pragma unroll
    for (int t = 0; t < 2; ++t)
#pragma unroll
      for (int r = 0; r < 16; ++r) {
        float s = st[t][r];
        float x = s * K1;
        float x2 = x * x;
        float ww = s * KW;
        float t1 = fmaf(x2, 0.13333334f, -0.33333334f);   // (tanh(x)/x - 1)/x2
        float y = fmaf(ww * x2, t1, ww);                  // cap*tanh(x)*log2e
        y = fminf(y, 72.134752f);                         // overflow guard
        if (!full) {
          const int koff = t * 32 + (r & 3) + 8 * (r >> 2);
          y = (koff <= qmb) ? y : -1e30f;
        }
        float pe = __builtin_amdgcn_exp2f(y);
        p[t][r] = pe;
        rs += pe;
      }
    rs += __shfl_xor(rs, 32);
    l_run += rs;
    // pack P to bf16 pairs (register-only: static uint array + bit_cast)
    uint pk[16];
#pragma unroll
    for (int t = 0; t < 2; ++t)
#pragma unroll
      for (int rr = 0; rr < 8; ++rr)
        pk[t * 8 + rr] = bfpack(p[t][2 * rr], p[t][2 * rr + 1]);
    uint rec[2][2][2];
#pragma unroll
    for (int t = 0; t < 2; ++t)
#pragma unroll
      for (int hh = 0; hh < 2; ++hh)
#pragma unroll
        for (int wb = 0; wb < 2; ++wb) {
          uint send = hi ? pk[t * 8 + 4 * hh + wb] : pk[t * 8 + 4 * hh + 2 + wb];
          rec[t][hh][wb] = __shfl_xor(send, 32);
        }
    // O^T += mfma(V^T, P^T): coalesced fragment loads
#pragma unroll
    for (int c = 0; c < 4; ++c) {
      const int t = c >> 1, hh = c & 1;
      u32x4 pu;
      pu[0] = hi ? rec[t][hh][0] : pk[t * 8 + 4 * hh + 0];
      pu[1] = hi ? rec[t][hh][1] : pk[t * 8 + 4 * hh + 1];
      pu[2] = hi ? pk[t * 8 + 4 * hh + 2] : rec[t][hh][0];
      pu[3] = hi ? pk[t * 8 + 4 * hh + 3] : rec[t][hh][1];
      bf16x8 pv = __builtin_bit_cast(bf16x8, pu);
#pragma unroll
      for (int dt = 0; dt < 4; ++dt) {
        bf16x8 vf = *(const bf16x8*)(vp + (c * 4 + dt) * 512);
        acc[dt] = __builtin_amdgcn_mfma_f32_32x32x16_bf16(vf, pv, acc[dt], 0, 0, 0);
      }
    }
  }

  // ---- 2-phase split-k merge (exact: both partials share identity scaling) ----
  if (w == 1) {
#pragma unroll
    for (int dt = 0; dt < 2; ++dt)
#pragma unroll
      for (int r = 0; r < 16; ++r)
        accbuf[(dt * 16 + r) * 64 + l] = acc[dt][r];
    lbuf[l] = l_run;
  }
  __syncthreads();
  if (w == 0) {
#pragma unroll
    for (int dt = 0; dt < 2; ++dt)
#pragma unroll
      for (int r = 0; r < 16; ++r)
        acc[dt][r] += accbuf[(dt * 16 + r) * 64 + l];
    l_run += lbuf[l];
  }
  __syncthreads();
  if (w == 1) {
#pragma unroll
    for (int dt = 0; dt < 2; ++dt)
#pragma unroll
      for (int r = 0; r < 16; ++r)
        accbuf[(dt * 16 + r) * 64 + l] = acc[dt + 2][r];
  }
  __syncthreads();
  if (w == 0) {
#pragma unroll
    for (int dt = 0; dt < 2; ++dt)
#pragma unroll
      for (int r = 0; r < 16; ++r)
        acc[dt + 2][r] += accbuf[(dt * 16 + r) * 64 + l];
    const float inv = __builtin_amdgcn_rcpf(l_run);
#pragma unroll
    for (int dt = 0; dt < 4; ++dt)
#pragma unroll
      for (int gg = 0; gg < 4; ++gg) {
        ushort4 o;
        o.x = f2bf(acc[dt][4 * gg + 0] * inv);
        o.y = f2bf(acc[dt][4 * gg + 1] * inv);
        o.z = f2bf(acc[dt][4 * gg + 2] * inv);
        o.w = f2bf(acc[dt][4 * gg + 3] * inv);
        const int d0 = dt * 32 + gg * 8 + hi * 4;
        *(ushort4*)(trbuf + ql * 140 + d0) = o;
      }
  }
  __syncthreads();
  // both waves store: 128 threads, 16 lanes per q-row, 8 rows per pass
#pragma unroll
  for (int i = 0; i < 4; ++i) {
    const int qr = i * 8 + (tid >> 4);
    const int c = tid & 15;
    uint4 v = *(const uint4*)(trbuf + qr * 140 + c * 8);
    *(uint4*)(obuf + (size_t)(b * NB_S + q0 + qr) * NB_D + h * 128 + c * 8) = v;
  }
}

// ---------------- host launch ----------------
extern "C" void kernel_launch(void* const* d_in, const int* in_sizes, int n_in,
                              void* d_out, int out_size, void* d_ws, size_t ws_size,
                              hipStream_t stream) {
  const float* hs   = (const float*)d_in[0];
  const float* cosb = (const float*)d_in[1];
  const float* sinb = (const float*)d_in[2];
  const float* Wq   = (const float*)d_in[3];
  const float* Wk   = (const float*)d_in[4];
  const float* Wv   = (const float*)d_in[5];
  const float* Wo   = (const float*)d_in[6];
  float* out = (float*)d_out;
  char* ws = (char*)d_ws;

  ushort* hsb  = (ushort*)(ws + 0);           // dead after gemm1; reused for Vf
  ushort* wqkv = (ushort*)(ws + 16777216);
  ushort* wob  = (ushort*)(ws + 29360128);
  ushort* qkvb = (ushort*)(ws + 37748736);
  ushort* kfb  = (ushort*)(ws + 62914560);    // 4MB
  ushort* ob   = (ushort*)(ws + 67108864);
  ushort* vfb  = (ushort*)(ws + 0);           // 4MB, overlays hsb after gemm1

  cvt_all<<<18432, 256, 0, stream>>>(hs, Wq, Wk, Wv, Wo, hsb, wqkv, wob);

  gemm_bt<<<768, 256, 0, stream>>>(hsb, wqkv, qkvb, nullptr, NB_M, NB_NQKV, NB_D, 24);

  rope_q<<<16384, 256, 0, stream>>>(qkvb, cosb, sinb);

  kv_repack<<<256, 256, 0, stream>>>(qkvb, cosb, sinb, kfb, vfb);

  attn_kernel<<<2048, 128, 0, stream>>>(qkvb, kfb, vfb, ob);

  gemm_bt<<<512, 256, 0, stream>>>(ob, wob, nullptr, out, NB_M, NB_D, NB_D, 16);
}

// Round 8
// 414.330 us; speedup vs baseline: 1.1774x; 1.1774x over previous
//
#include <hip/hip_runtime.h>
#include <hip/hip_bf16.h>
#include <stdint.h>

typedef __bf16 bf16x8 __attribute__((ext_vector_type(8)));
typedef ushort u16x8 __attribute__((ext_vector_type(8)));
typedef uint u32x4 __attribute__((ext_vector_type(4)));
typedef float f32x4 __attribute__((ext_vector_type(4)));
typedef float f32x16 __attribute__((ext_vector_type(16)));

#define NB_H 16
#define NB_KV 4
#define NB_HD 128
#define NB_B 2
#define NB_S 2048
#define NB_D 2048
#define NB_M (NB_B*NB_S)   /* 4096 */
#define NB_NQKV 3072
#define CAPF 50.0f
#define SCALEF 0.08838834764831845f

__device__ __forceinline__ ushort f2bf(float x){
  uint32_t u = __float_as_uint(x);
  u += 0x7fffu + ((u >> 16) & 1u);
  return (ushort)(u >> 16);
}
__device__ __forceinline__ float bf2f(ushort u){
  return __uint_as_float(((uint32_t)u) << 16);
}
__device__ __forceinline__ uint bfpack(float lo, float hi2){
  uint a = (uint)__builtin_bit_cast(unsigned short, (__bf16)lo);
  uint b = (uint)__builtin_bit_cast(unsigned short, (__bf16)hi2);
  return a | (b << 16);
}
__device__ __forceinline__ void gload_lds16(const void* g, void* l){
  __builtin_amdgcn_global_load_lds(
      (const __attribute__((address_space(1))) uint32_t*)g,
      (__attribute__((address_space(3))) uint32_t*)l, 16, 0, 0);
}

// ---------------- fused fp32 -> bf16 conversion (all 5 tensors, 1 launch) ----------------
__global__ __launch_bounds__(256) void cvt_all(const float* __restrict__ hs,
                                               const float* __restrict__ wq,
                                               const float* __restrict__ wk,
                                               const float* __restrict__ wv,
                                               const float* __restrict__ wo,
                                               ushort* __restrict__ hsb,
                                               ushort* __restrict__ wqkv,
                                               ushort* __restrict__ wob){
  int q = blockIdx.x * blockDim.x + threadIdx.x;   // grid sized exactly
  const float* src; ushort* dst; int i;
  if (q < 2097152)      { src = hs; dst = hsb;            i = q; }
  else if (q < 3145728) { src = wq; dst = wqkv;           i = q - 2097152; }
  else if (q < 3407872) { src = wk; dst = wqkv + 4194304; i = q - 3145728; }
  else if (q < 3670016) { src = wv; dst = wqkv + 5242880; i = q - 3407872; }
  else                  { src = wo; dst = wob;            i = q - 3670016; }
  float4 v = ((const float4*)src)[i];
  ushort4 o;
  o.x = f2bf(v.x); o.y = f2bf(v.y); o.z = f2bf(v.z); o.w = f2bf(v.w);
  ((ushort4*)dst)[i] = o;
}

// ---------------- bf16 GEMM: C[M][N] = A[M][K] * B[N][K]^T (1D grid + XCD swizzle) ----------------
__global__ __launch_bounds__(256) void gemm_bt(const ushort* __restrict__ A,
                                               const ushort* __restrict__ Bw,
                                               ushort* __restrict__ Cb,
                                               float* __restrict__ Cf,
                                               int M, int N, int K, int nbx){
  int nwg = gridDim.x;
  int cpx = nwg >> 3;
  int wg = blockIdx.x;
  int swz = (wg & 7) * cpx + (wg >> 3);
  int bx = swz % nbx, by = swz / nbx;

  __shared__ ushort As[128 * 32];
  __shared__ ushort Bs[128 * 32];
  int tid = threadIdx.x;
  int w = tid >> 6, l = tid & 63;
  int lr = l & 15, lk = l >> 4;
  int row0 = by * 128, col0 = bx * 128;
  int wm = w >> 1, wn = w & 1;

  f32x4 acc[4][4];
#pragma unroll
  for (int mi = 0; mi < 4; ++mi)
#pragma unroll
    for (int nj = 0; nj < 4; ++nj)
      acc[mi][nj] = f32x4{0.f, 0.f, 0.f, 0.f};

  for (int k0 = 0; k0 < K; k0 += 32) {
#pragma unroll
    for (int c = 0; c < 2; ++c) {
      int off = w * 2048 + c * 1024 + l * 16;
      int r = off >> 6;
      int cb = off & 63;
      gload_lds16(A + (size_t)(row0 + r) * K + k0 + (cb >> 1), (char*)As + off);
      gload_lds16(Bw + (size_t)(col0 + r) * K + k0 + (cb >> 1), (char*)Bs + off);
    }
    __syncthreads();
    bf16x8 af[4], bfr[4];
#pragma unroll
    for (int mi = 0; mi < 4; ++mi)
      af[mi] = *(const bf16x8*)(As + (wm * 64 + mi * 16 + lr) * 32 + lk * 8);
#pragma unroll
    for (int nj = 0; nj < 4; ++nj)
      bfr[nj] = *(const bf16x8*)(Bs + (wn * 64 + nj * 16 + lr) * 32 + lk * 8);
#pragma unroll
    for (int mi = 0; mi < 4; ++mi)
#pragma unroll
      for (int nj = 0; nj < 4; ++nj)
        acc[mi][nj] = __builtin_amdgcn_mfma_f32_16x16x32_bf16(af[mi], bfr[nj], acc[mi][nj], 0, 0, 0);
    __syncthreads();
  }

#pragma unroll
  for (int mi = 0; mi < 4; ++mi)
#pragma unroll
    for (int nj = 0; nj < 4; ++nj)
#pragma unroll
      for (int i = 0; i < 4; ++i) {
        int r = row0 + wm * 64 + mi * 16 + lk * 4 + i;
        int c = col0 + wn * 64 + nj * 16 + lr;
        float v = acc[mi][nj][i];
        if (Cb) Cb[(size_t)r * N + c] = f2bf(v);
        else    Cf[(size_t)r * N + c] = v;
      }
}

// ---------------- RoPE in-place on Q heads only (K's RoPE is fused into kv_repack) ----------------
__global__ __launch_bounds__(256) void rope_q(ushort* __restrict__ qkv,
                                              const float* __restrict__ cosb,
                                              const float* __restrict__ sinb){
  int idx = blockIdx.x * blockDim.x + threadIdx.x;   // NB_M*16*64 exactly
  int row = idx >> 10;
  int rem = idx & 1023;
  int head = rem >> 6;        // 0..15
  int d = rem & 63;
  size_t base = (size_t)row * NB_NQKV + head * 128 + d;
  float a = bf2f(qkv[base]);
  float b = bf2f(qkv[base + 64]);
  float c = cosb[row * 128 + d];
  float s = sinb[row * 128 + d];
  qkv[base]      = f2bf(a * c - b * s);
  qkv[base + 64] = f2bf(b * c + a * s);
}

// ---------------- K/V repack into MFMA-fragment layout (+ RoPE on K) ----------------
// grid: B*KV*(S/64) = 256 blocks x 256 thr. Per (b,kvh,kt64):
//   Kf[(t,dc)][lane] = roped K[s0+32t+ql][16dc+8hi+j]   (16 frags x 64 lanes x 8 bf16)
//   Vf[(c,dt)][lane] = V[s0+(2c+hi)*8+j][32dt+ql]
__global__ __launch_bounds__(256) void kv_repack(const ushort* __restrict__ qkv,
                                                 const float* __restrict__ cosb,
                                                 const float* __restrict__ sinb,
                                                 ushort* __restrict__ Kf,
                                                 ushort* __restrict__ Vf){
  __shared__ ushort Ks[64 * 136];
  __shared__ ushort Vs[64 * 136];
  const int blk = blockIdx.x;
  const int kt = blk & 31, kvh = (blk >> 5) & 3, b = blk >> 7;
  const int s0 = kt * 64;
  const int tid = threadIdx.x;
  {
    const int r = tid >> 2, c0 = tid & 3;
    const ushort* src = qkv + (size_t)(b * NB_S + s0 + r) * NB_NQKV + kvh * 128;
#pragma unroll
    for (int k = 0; k < 4; ++k) {
      int c = c0 + k * 4;
      *(u16x8*)(Ks + r * 136 + c * 8) = *(const u16x8*)(src + 2048 + c * 8);
      *(u16x8*)(Vs + r * 136 + c * 8) = *(const u16x8*)(src + 2560 + c * 8);
    }
  }
  __syncthreads();
  const int w = tid >> 6, l = tid & 63, ql = l & 31, hi = l >> 5;
  const size_t fbase = (size_t)((b * NB_KV + kvh) * 32 + kt) * 8192;
  // K fragments (with RoPE)
#pragma unroll
  for (int i = 0; i < 4; ++i) {
    const int idx = i * 4 + w;          // = t*8 + dc
    const int t = idx >> 3, dc = idx & 7;
    const int row = t * 32 + ql;
    const int d0 = dc * 16 + hi * 8;
    u16x8 a  = *(const u16x8*)(Ks + row * 136 + d0);
    u16x8 p2 = *(const u16x8*)(Ks + row * 136 + (d0 ^ 64));
    const float* cr = cosb + (size_t)(b * NB_S + s0 + row) * 128 + d0;
    const float* sr = sinb + (size_t)(b * NB_S + s0 + row) * 128 + d0;
    const float sgn = (dc < 4) ? -1.f : 1.f;
    u16x8 outv;
#pragma unroll
    for (int j2 = 0; j2 < 8; ++j2) {
      float kv = bf2f(a[j2]), pv = bf2f(p2[j2]);
      outv[j2] = f2bf(fmaf(sgn * pv, sr[j2], kv * cr[j2]));
    }
    *(u16x8*)(Kf + fbase + ((size_t)idx * 64 + l) * 8) = outv;
  }
  // V fragments
#pragma unroll
  for (int i = 0; i < 4; ++i) {
    const int idx = i * 4 + w;          // = c*4 + dt
    const int c = idx >> 2, dt = idx & 3;
    const int col = dt * 32 + ql;
    u16x8 outv;
#pragma unroll
    for (int j2 = 0; j2 < 8; ++j2)
      outv[j2] = Vs[((2 * c + hi) * 8 + j2) * 136 + col];
    *(u16x8*)(Vf + fbase + ((size_t)idx * 64 + l) * 8) = outv;
  }
}

// ---------------- flash attention v7: fragment-layout K/V, barrier-free, unconstrained regalloc ----------------
// grid: 2048 blocks x 128 thr (2 waves). Block = one 32-row q-tile; waves split k-tiles
// (interleaved) and merge exactly at the end (no-max softmax).
// t-sequential inner structure keeps peak live-regs ~145 (no spill without launch-bounds cap).
__global__ __launch_bounds__(128) void attn_kernel(const ushort* __restrict__ qkv,
                                                   const ushort* __restrict__ Kf,
                                                   const ushort* __restrict__ Vf,
                                                   ushort* __restrict__ obuf){
  __shared__ float accbuf[4096];      // single-phase split-k merge (16KB)
  __shared__ float lbuf[64];
  __shared__ ushort trbuf[32 * 140];  // epilogue transpose (8.96KB)
  const int tid = threadIdx.x;
  const int w = tid >> 6, l = tid & 63;
  const int ql = l & 31, hi = l >> 5;
  const int blk = blockIdx.x;
  const int g = blk & 7;
  const int inner = blk >> 3;
  const int h_lo = inner & 3;
  const int qtile = 63 - (inner >> 2);
  const int b = g >> 2, kvh = g & 3;
  const int h = kvh * 4 + h_lo;
  const int q0 = qtile * 32;
  const int q = q0 + ql;
  const int nkt = (q0 + 95) >> 6;     // tiles with s0 <= q0+31

  const ushort* Kfb = Kf + (size_t)(b * NB_KV + kvh) * 262144 + l * 8;
  const ushort* Vfb = Vf + (size_t)(b * NB_KV + kvh) * 262144 + l * 8;

  // Q fragments: plain vector loads (Q pre-roped by rope_q)
  bf16x8 qf[8];
  {
    const ushort* qrow = qkv + (size_t)(b * NB_S + q) * NB_NQKV + h * 128 + hi * 8;
#pragma unroll
    for (int dc = 0; dc < 8; ++dc)
      qf[dc] = *(const bf16x8*)(qrow + dc * 16);
  }

  f32x16 acc[4];   // O^T accumulator: acc[dt] = 32d x 32q tile, col q = ql
#pragma unroll
  for (int dt = 0; dt < 4; ++dt)
#pragma unroll
    for (int r = 0; r < 16; ++r) acc[dt][r] = 0.f;
  float rs_acc = 0.f;

  const float K1 = SCALEF / CAPF;                  // s -> x
  const float KW = SCALEF * 1.4426950408889634f;   // s -> w (= cap*log2e*x)

  for (int kt = w; kt < nkt; kt += 2) {
    const int s0 = kt * 64;
    const ushort* kp = Kfb + (size_t)kt * 8192;
    const ushort* vp = Vfb + (size_t)kt * 8192;
    const bool full = (s0 + 63 <= q0);             // wave-uniform
    const int qmb = q - s0 - 4 * hi;               // mask: koff <= qmb
#pragma unroll
    for (int t = 0; t < 2; ++t) {
      // S^T = mfma(K, Q): coalesced 16B/lane fragment loads (L2-resident)
      f32x16 st;
#pragma unroll
      for (int r = 0; r < 16; ++r) st[r] = 0.f;
#pragma unroll
      for (int dc = 0; dc < 8; ++dc) {
        bf16x8 kf = *(const bf16x8*)(kp + (t * 8 + dc) * 512);
        st = __builtin_amdgcn_mfma_f32_32x32x16_bf16(kf, qf[dc], st, 0, 0, 0);
      }
      // fused poly-tanh soft-cap + exp2 softmax (no max subtraction: capped <= 50)
      float p[16];
#pragma unroll
      for (int r = 0; r < 16; ++r) {
        float s = st[r];
        float x = s * K1;
        float x2 = x * x;
        float ww = s * KW;
        float t1 = fmaf(x2, 0.13333334f, -0.33333334f);   // (tanh(x)/x - 1)/x2
        float y = fmaf(ww * x2, t1, ww);                  // cap*tanh(x)*log2e
        y = fminf(y, 72.134752f);                         // overflow guard
        if (!full) {
          const int koff = t * 32 + (r & 3) + 8 * (r >> 2);
          y = (koff <= qmb) ? y : -1e30f;
        }
        float pe = __builtin_amdgcn_exp2f(y);
        p[r] = pe;
        rs_acc += pe;
      }
      // pack P to bf16 pairs and exchange 4 words across half-waves
      uint pk[8];
#pragma unroll
      for (int rr = 0; rr < 8; ++rr)
        pk[rr] = bfpack(p[2 * rr], p[2 * rr + 1]);
      uint rec[2][2];
#pragma unroll
      for (int hh = 0; hh < 2; ++hh)
#pragma unroll
        for (int wb = 0; wb < 2; ++wb) {
          uint send = hi ? pk[4 * hh + wb] : pk[4 * hh + 2 + wb];
          rec[hh][wb] = __shfl_xor(send, 32);
        }
      // O^T += mfma(V^T, P^T) for this t's two k-chunks
#pragma unroll
      for (int hh = 0; hh < 2; ++hh) {
        const int c = t * 2 + hh;
        u32x4 pu;
        pu[0] = hi ? rec[hh][0] : pk[4 * hh + 0];
        pu[1] = hi ? rec[hh][1] : pk[4 * hh + 1];
        pu[2] = hi ? pk[4 * hh + 2] : rec[hh][0];
        pu[3] = hi ? pk[4 * hh + 3] : rec[hh][1];
        bf16x8 pv = __builtin_bit_cast(bf16x8, pu);
#pragma unroll
        for (int dt = 0; dt < 4; ++dt) {
          bf16x8 vf = *(const bf16x8*)(vp + (c * 4 + dt) * 512);
          acc[dt] = __builtin_amdgcn_mfma_f32_32x32x16_bf16(vf, pv, acc[dt], 0, 0, 0);
        }
      }
    }
  }
  float l_run = rs_acc + __shfl_xor(rs_acc, 32);

  // ---- single-phase split-k merge (exact: both partials share identity scaling) ----
  if (w == 1) {
#pragma unroll
    for (int dt = 0; dt < 4; ++dt)
#pragma unroll
      for (int r = 0; r < 16; ++r)
        accbuf[(dt * 16 + r) * 64 + l] = acc[dt][r];
    lbuf[l] = l_run;
  }
  __syncthreads();
  if (w == 0) {
#pragma unroll
    for (int dt = 0; dt < 4; ++dt)
#pragma unroll
      for (int r = 0; r < 16; ++r)
        acc[dt][r] += accbuf[(dt * 16 + r) * 64 + l];
    l_run += lbuf[l];
    const float inv = __builtin_amdgcn_rcpf(l_run);
#pragma unroll
    for (int dt = 0; dt < 4; ++dt)
#pragma unroll
      for (int gg = 0; gg < 4; ++gg) {
        ushort4 o;
        o.x = f2bf(acc[dt][4 * gg + 0] * inv);
        o.y = f2bf(acc[dt][4 * gg + 1] * inv);
        o.z = f2bf(acc[dt][4 * gg + 2] * inv);
        o.w = f2bf(acc[dt][4 * gg + 3] * inv);
        const int d0 = dt * 32 + gg * 8 + hi * 4;
        *(ushort4*)(trbuf + ql * 140 + d0) = o;
      }
  }
  __syncthreads();
  // both waves store: 128 threads, 16 lanes per q-row, 8 rows per pass
#pragma unroll
  for (int i = 0; i < 4; ++i) {
    const int qr = i * 8 + (tid >> 4);
    const int c = tid & 15;
    uint4 v = *(const uint4*)(trbuf + qr * 140 + c * 8);
    *(uint4*)(obuf + (size_t)(b * NB_S + q0 + qr) * NB_D + h * 128 + c * 8) = v;
  }
}

// ---------------- host launch ----------------
extern "C" void kernel_launch(void* const* d_in, const int* in_sizes, int n_in,
                              void* d_out, int out_size, void* d_ws, size_t ws_size,
                              hipStream_t stream) {
  const float* hs   = (const float*)d_in[0];
  const float* cosb = (const float*)d_in[1];
  const float* sinb = (const float*)d_in[2];
  const float* Wq   = (const float*)d_in[3];
  const float* Wk   = (const float*)d_in[4];
  const float* Wv   = (const float*)d_in[5];
  const float* Wo   = (const float*)d_in[6];
  float* out = (float*)d_out;
  char* ws = (char*)d_ws;

  ushort* hsb  = (ushort*)(ws + 0);           // dead after gemm1; reused for Vf
  ushort* wqkv = (ushort*)(ws + 16777216);
  ushort* wob  = (ushort*)(ws + 29360128);
  ushort* qkvb = (ushort*)(ws + 37748736);
  ushort* kfb  = (ushort*)(ws + 62914560);    // 4MB
  ushort* ob   = (ushort*)(ws + 67108864);
  ushort* vfb  = (ushort*)(ws + 0);           // 4MB, overlays hsb after gemm1

  cvt_all<<<18432, 256, 0, stream>>>(hs, Wq, Wk, Wv, Wo, hsb, wqkv, wob);

  gemm_bt<<<768, 256, 0, stream>>>(hsb, wqkv, qkvb, nullptr, NB_M, NB_NQKV, NB_D, 24);

  rope_q<<<16384, 256, 0, stream>>>(qkvb, cosb, sinb);

  kv_repack<<<256, 256, 0, stream>>>(qkvb, cosb, sinb, kfb, vfb);

  attn_kernel<<<2048, 128, 0, stream>>>(qkvb, kfb, vfb, ob);

  gemm_bt<<<512, 256, 0, stream>>>(ob, wob, nullptr, out, NB_M, NB_D, NB_D, 16);
}